// Round 12
// baseline (58.107 us; speedup 1.0000x reference)
//
#include <hip/hip_runtime.h>

typedef float __attribute__((ext_vector_type(4))) f32x4;
typedef unsigned int u32;
typedef u32 __attribute__((ext_vector_type(4))) u32x4;

// OUT[n, c=j*8+k, h, w] = sum_{a,m,b} W[j,a,m,b,k] * T[n,(j+a-1)*4+m, (h-1)%28, (w+b-2)%28]
//   T[n,cc,h,w] = x[n,cc,h,w] + x[n,cc+128,h,w]
//   (j+a-1) outside [0,32) -> zero; (w+b-1) outside [0,28) -> zero (w unfold pad)
//
// R12 = R11 with a wave-autonomous output tail (1 barrier per block, was 5).
//   R11 analysis: HBM ~28us / VALU ~23us / LDS ~17us per CU but dur 50us -> the wall is
//   phase serialization from block-wide barriers (4 resident blocks = only 4 phase
//   contexts). Here each wave owns channels 64*(wv&3)..+63 of row h0+(wv>>2) (lane =
//   channel), so the store-coalescing LDS round-trip is private per wave: write own
//   16-ch strip chunk -> wave-local lgkmcnt(0) -> coalesced read-back -> 112B-run global
//   stores, x4 chunks. No block sync after staging -> 32 resident waves spread freely.
// Verified pieces kept byte-for-byte: bf16-pair m-packed LDS + v_dot2_f32_bf16 compute
//   (absmax 0.5, R7/R9/R10/R11), quad-slot swizzle q^(g&7) (R2: 0 conflicts), 224B-run
//   coalesced staging (R10/R11).
// LDS: input 2x2048 dwords (16 KB) + 8 wave strips x 16ch x 29 f32 (14.8 KB) = 31.2 KB
//   -> 4 blocks/CU = 32 waves/CU.

__device__ __forceinline__ u32 pack2bf(float lo, float hi) {
    u32 a = __float_as_uint(lo), b = __float_as_uint(hi);
    a = (a + 0x7FFFu + ((a >> 16) & 1u)) >> 16;   // RNE round to bf16
    b = (b + 0x7FFFu + ((b >> 16) & 1u)) >> 16;
    return a | (b << 16);
}

__device__ __forceinline__ float dot2bf(u32 t2, u32 w2, float acc) {
    asm("v_dot2_f32_bf16 %0, %1, %2, %0" : "+v"(acc) : "v"(t2), "v"(w2));
    return acc;
}

__global__ __launch_bounds__(512, 8) void fused_shift_conv(
    const float* __restrict__ x, const float* __restrict__ Wt, float* __restrict__ out)
{
    __shared__ __align__(16) u32 L[4096 + 8 * 464];   // input 16 KB + 8 out-strips

    const int tid = threadIdx.x;
    const int blk = blockIdx.x;
    const int n   = blk / 14;
    const int b2  = blk - n * 14;
    const int h0  = b2 * 2;                 // output rows h0, h0+1 (no wrap)

    const float* xn = x + (size_t)n * 200704;

    // ---- staging: 64 ch-pairs x 2 input rows x 7 quads = 896 items, 224 B runs ----
    #pragma unroll
    for (int it = 0; it < 2; ++it) {
        const int f = tid + it * 512;
        if (f < 896) {
            const int p     = f / 14;       // channel pair 0..63 (ch 2p, 2p+1)
            const int rem14 = f - p * 14;
            const int row   = rem14 / 7;    // input row index 0..1
            const int q     = rem14 - row * 7;
            int hs = h0 - 1 + row;          // wraps only when h0==0 && row==0
            hs = hs < 0 ? 27 : hs;
            const float* b0 = xn + (2 * p) * 784 + hs * 28 + q * 4;
            const f32x4 l0 = *(const f32x4*)b0;                  // ch 2p,   low half
            const f32x4 l1 = *(const f32x4*)(b0 + 784);          // ch 2p+1, low half
            const f32x4 u0 = *(const f32x4*)(b0 + 100352);       // high halves
            const f32x4 u1 = *(const f32x4*)(b0 + 784 + 100352);
            const f32x4 s0 = l0 + u0, s1 = l1 + u1;
            u32x4 wv;
            #pragma unroll
            for (int e = 0; e < 4; ++e) wv[e] = pack2bf(s0[e], s1[e]);
            const int sw = (p >> 1) & 7;    // g = p>>1
            *(u32x4*)&L[row * 2048 + p * 32 + ((q ^ sw) << 2)] = wv;
        }
    }

    // ---- per-thread weights: slice s_ computes row h0+s_, thread owns c = j*8+k ----
    const int t  = tid & 255;
    const int s_ = tid >> 8;                // slice 0/1
    const int j = t >> 3, k = t & 7;
    u32 w2[3][2][3];                        // [a][m-pair][tap], bf16-pair packed
    {
        const float* wp = Wt + j * 288 + k; // W[j,a,m,b,k] strides 288/96/24/8/1
        #pragma unroll
        for (int a = 0; a < 3; ++a)
            #pragma unroll
            for (int m2 = 0; m2 < 2; ++m2)
                #pragma unroll
                for (int bb = 0; bb < 3; ++bb)
                    w2[a][m2][bb] = pack2bf(wp[a*96 + (2*m2  )*24 + bb*8],
                                            wp[a*96 + (2*m2+1)*24 + bb*8]);
    }
    if (j == 0) {
        #pragma unroll
        for (int m2 = 0; m2 < 2; ++m2)
            #pragma unroll
            for (int bb = 0; bb < 3; ++bb) w2[0][m2][bb] = 0u;
    }
    if (j == 31) {
        #pragma unroll
        for (int m2 = 0; m2 < 2; ++m2)
            #pragma unroll
            for (int bb = 0; bb < 3; ++bb) w2[2][m2][bb] = 0u;
    }

    __syncthreads();                        // the ONLY block-wide barrier

    // ---- compute (verified body): 42 ds_read_b128 + ~492 dot2 ----
    const u32* Bs = L + s_ * 2048;
    float acc[28];
    #pragma unroll
    for (int w = 0; w < 28; ++w) acc[w] = 0.f;

    #pragma unroll
    for (int a = 0; a < 3; ++a) {
        int g = j + a - 1;
        g = g < 0 ? 0 : (g > 31 ? 31 : g);  // weights already zeroed for OOB
        const int s = g & 7;
        #pragma unroll
        for (int m2 = 0; m2 < 2; ++m2) {
            const int rowd = (g * 2 + m2) * 32;
            const u32 t2 = w2[a][m2][2], t1 = w2[a][m2][1], t0 = w2[a][m2][0];
            #pragma unroll
            for (int qb = 0; qb < 7; ++qb) {
                const u32x4 v = *(const u32x4*)&Bs[rowd + ((qb ^ s) << 2)];
                #pragma unroll
                for (int e = 0; e < 4; ++e) {
                    const int wp_ = qb * 4 + e;                              // source col w'
                    if (wp_ != 27) acc[wp_] = dot2bf(v[e], t2, acc[wp_]);    // b=2 tap
                    acc[(wp_ + 1) % 28] = dot2bf(v[e], t1, acc[(wp_ + 1) % 28]); // b=1
                    if (wp_ != 26) acc[(wp_ + 2) % 28] = dot2bf(v[e], t0, acc[(wp_ + 2) % 28]); // b=0
                }
            }
        }
    }

    // ---- wave-autonomous output: 4 chunks of 16 channels via private LDS strip ----
    const int wv8  = tid >> 6;              // wave 0..7
    const int lane = tid & 63;              // lane = channel - 64*(wv8&3)
    float* Ls = (float*)(L + 4096) + wv8 * 464;     // 16 ch x pitch 29
    float* outn = out + (size_t)n * 200704 + (size_t)(h0 + s_) * 28;
    const int cb = (wv8 & 3) * 64;          // channel base of this wave

    const int ch0_ = lane / 7,        q0_ = lane % 7;          // read-back item lane
    const int it1  = lane + 64;
    const int ch1_ = it1 / 7,         q1_ = it1 % 7;           // valid when it1 < 112

    #pragma unroll
    for (int cc = 0; cc < 4; ++cc) {
        if ((lane >> 4) == cc) {            // 16 owner lanes dump their row
            float* dst = Ls + (lane & 15) * 29;
            #pragma unroll
            for (int qq = 0; qq < 7; ++qq) {
                f32x4 o;
                o.x = acc[qq * 4 + 0];
                o.y = acc[qq * 4 + 1];
                o.z = acc[qq * 4 + 2];
                o.w = acc[qq * 4 + 3];
                *(f32x4*)(dst + qq * 4) = o;
            }
        }
        asm volatile("s_waitcnt lgkmcnt(0)" ::: "memory");   // wave-local: writes visible
        {
            const f32x4 v = *(const f32x4*)(Ls + ch0_ * 29 + q0_ * 4);
            *(f32x4*)(outn + (size_t)(cb + cc * 16 + ch0_) * 784 + q0_ * 4) = v;
        }
        if (it1 < 112) {
            const f32x4 v = *(const f32x4*)(Ls + ch1_ * 29 + q1_ * 4);
            *(f32x4*)(outn + (size_t)(cb + cc * 16 + ch1_) * 784 + q1_ * 4) = v;
        }
        asm volatile("s_waitcnt lgkmcnt(0)" ::: "memory");   // reads retired before reuse
    }
}

extern "C" void kernel_launch(void* const* d_in, const int* in_sizes, int n_in,
                              void* d_out, int out_size, void* d_ws, size_t ws_size,
                              hipStream_t stream) {
    const float* x  = (const float*)d_in[0];   // (128,256,28,28) f32
    const float* Wt = (const float*)d_in[1];   // (32,3,4,3,8)   f32
    float* out      = (float*)d_out;           // (128,256,28,28) f32

    const int nbatch = in_sizes[0] / 200704;   // 128
    fused_shift_conv<<<nbatch * 14, 512, 0, stream>>>(x, Wt, out);  // (n, h-pair)
}